// Round 10
// baseline (86.480 us; speedup 1.0000x reference)
//
#include <hip/hip_runtime.h>

#define BB 8
#define LL 32768
#define DD 64

typedef float f4 __attribute__((ext_vector_type(4)));
typedef unsigned long long u64x2 __attribute__((ext_vector_type(2)));

// ws layout:
// [0, 256K)            : double part[BB][CHUNKS_Q][DD] partial q-sums (fully written by k1)
// [256K, 256K+BB*LL*8) : double scores[BB*LL]  (2 MiB, fully written by k2)

#define OUT_F4 (BB * LL * DD / 4)  // 4,194,304 float4s in out
#define CHUNKS_Q 64                // blocks per batch in k_reduce_q
#define ROWS_Q (LL / CHUNKS_Q)     // 512 rows per block

// ---------------- Kernel 1: per-chunk partials of sum_l relu(q)+eps ----------------
// 512 blocks x 256 threads (round-8 structure). Zero-fills the FIRST half of out.
__global__ __launch_bounds__(256) void k_reduce_q(const float* __restrict__ q,
                                                  double* __restrict__ part,
                                                  float* __restrict__ out) {
    {
        f4 z = (f4)(0.0f);
        f4* oz = (f4*)out + (size_t)blockIdx.x * 4096 + threadIdx.x;
#pragma unroll
        for (int i = 0; i < 16; ++i) oz[i * 256] = z;
    }

    int b     = blockIdx.x >> 6;           // /CHUNKS_Q
    int chunk = blockIdx.x & (CHUNKS_Q - 1);
    int quad  = threadIdx.x & 15;          // which float4 of the 64-wide row
    int rowg  = threadIdx.x >> 4;          // 16 row-groups

    const f4* qb = (const f4*)(q + (size_t)b * LL * DD);
    const f4* base = qb + (size_t)(chunk * ROWS_Q + rowg) * 16 + quad;

    double a0 = 0.0, a1 = 0.0, a2 = 0.0, a3 = 0.0;
    f4 vb[8];
#pragma unroll
    for (int batch = 0; batch < 4; ++batch) {
#pragma unroll
        for (int j = 0; j < 8; ++j)
            vb[j] = base[(size_t)(batch * 8 + j) * 256];   // 16 rows = 256 f4 stride
#pragma unroll
        for (int j = 0; j < 8; ++j) {
            a0 += (double)fmaxf(vb[j].x, 0.0f) + 1e-3;
            a1 += (double)fmaxf(vb[j].y, 0.0f) + 1e-3;
            a2 += (double)fmaxf(vb[j].z, 0.0f) + 1e-3;
            a3 += (double)fmaxf(vb[j].w, 0.0f) + 1e-3;
        }
    }

    __shared__ double lds[16][16][5];   // [5] pads away bank conflicts
    lds[rowg][quad][0] = a0; lds[rowg][quad][1] = a1;
    lds[rowg][quad][2] = a2; lds[rowg][quad][3] = a3;
    __syncthreads();
    for (int s = 8; s > 0; s >>= 1) {
        if (rowg < s) {
            lds[rowg][quad][0] += lds[rowg + s][quad][0];
            lds[rowg][quad][1] += lds[rowg + s][quad][1];
            lds[rowg][quad][2] += lds[rowg + s][quad][2];
            lds[rowg][quad][3] += lds[rowg + s][quad][3];
        }
        __syncthreads();
    }
    if (rowg == 0) {
        double* pp = part + ((size_t)b * CHUNKS_Q + chunk) * DD;
        pp[quad * 4 + 0] = lds[0][quad][0];
        pp[quad * 4 + 1] = lds[0][quad][1];
        pp[quad * 4 + 2] = lds[0][quad][2];
        pp[quad * 4 + 3] = lds[0][quad][3];
    }
}

// ---------------- Kernel 2: reduce partials -> rq, then scores ----------------
// 1024 blocks x 256 threads (round-8 structure). Zero-fills the SECOND half of out.
__global__ __launch_bounds__(256) void k_scores(const float* __restrict__ k,
                                                const double* __restrict__ part,
                                                double* __restrict__ scores,
                                                float* __restrict__ out) {
    __shared__ double s_part[4][DD];
    __shared__ double s_rq[DD];

    {
        f4 z = (f4)(0.0f);
        f4* oz = (f4*)out + (size_t)(OUT_F4 / 2)
               + (size_t)blockIdx.x * 2048 + threadIdx.x;
#pragma unroll
        for (int i = 0; i < 8; ++i) oz[i * 256] = z;
    }

    const int RPB = 256;
    int b     = blockIdx.x >> 7;          // /(LL/RPB)
    int chunk = blockIdx.x & 127;

    {
        int d = threadIdx.x & 63;
        int g = threadIdx.x >> 6;   // 0..3
        const double* pp = part + (size_t)b * CHUNKS_Q * DD;
        double acc = 0.0;
#pragma unroll
        for (int j = 0; j < 16; ++j)
            acc += pp[(size_t)(g * 16 + j) * DD + d];
        s_part[g][d] = acc;
    }
    __syncthreads();
    if (threadIdx.x < DD) {
        int d = threadIdx.x;
        s_rq[d] = (s_part[0][d] + s_part[1][d]) + (s_part[2][d] + s_part[3][d]);
    }
    __syncthreads();

    int sub   = threadIdx.x & 15;
    int rowIn = threadIdx.x >> 4;

    double r0 = s_rq[sub * 4 + 0];
    double r1 = s_rq[sub * 4 + 1];
    double r2 = s_rq[sub * 4 + 2];
    double r3 = s_rq[sub * 4 + 3];

    const f4* kb = (const f4*)(k + (size_t)b * LL * DD);
    int l0 = chunk * RPB;
    const f4* base = kb + (size_t)(l0 + rowIn) * 16 + sub;

    f4 vb[8];
    double sv[8];
#pragma unroll
    for (int batch = 0; batch < 2; ++batch) {
#pragma unroll
        for (int i = 0; i < 8; ++i)
            vb[i] = base[(size_t)(batch * 8 + i) * 256];
#pragma unroll
        for (int i = 0; i < 8; ++i) {
            sv[i] = r0 * ((double)fmaxf(vb[i].x, 0.0f) + 1e-3)
                  + r1 * ((double)fmaxf(vb[i].y, 0.0f) + 1e-3)
                  + r2 * ((double)fmaxf(vb[i].z, 0.0f) + 1e-3)
                  + r3 * ((double)fmaxf(vb[i].w, 0.0f) + 1e-3);
        }
#pragma unroll
        for (int i = 0; i < 8; ++i) {
            double s = sv[i];
            s += __shfl_xor(s, 1, 16);
            s += __shfl_xor(s, 2, 16);
            s += __shfl_xor(s, 4, 16);
            s += __shfl_xor(s, 8, 16);
            if (sub == 0)
                scores[(size_t)b * LL + l0 + rowIn + 16 * (batch * 8 + i)] = s;
        }
    }
}

// ---------------- Kernel 3: radix select + gather selected V rows ----------------
// One block per batch, 1024 threads, 32 keys/thread.
// v2: survivor bitmask (later passes touch ~0 keys) + wave-level suffix scan
//     (~7 barriers/pass instead of ~21). Early exit on unique bucket.
#define NCOPY 16
#define HSTRIDE 257
#define MAXSEL 96
__global__ __launch_bounds__(1024) void k_select_gather(const double* __restrict__ scores,
                                                        const int* __restrict__ topk_p,
                                                        const float* __restrict__ v,
                                                        float* __restrict__ out) {
    const int T = 1024;
    const int KPT = LL / T;  // 32
    int b   = blockIdx.x;
    int tid = threadIdx.x;

    const u64x2* sb2 = (const u64x2*)(scores + (size_t)b * LL);

    unsigned long long key[KPT];
    unsigned long long myAnd = ~0ULL, myOr = 0ULL;
#pragma unroll
    for (int j = 0; j < KPT / 2; ++j) {
        u64x2 p = sb2[tid + j * T];
        key[2 * j]     = p.x;
        key[2 * j + 1] = p.y;
        myAnd &= p.x & p.y;
        myOr  |= p.x | p.y;
    }

    __shared__ unsigned long long sAnd[16], sOr[16];
#pragma unroll
    for (int off = 32; off >= 1; off >>= 1) {
        myAnd &= __shfl_down(myAnd, off);
        myOr  |= __shfl_down(myOr, off);
    }
    int wave = tid >> 6;
    if ((tid & 63) == 0) { sAnd[wave] = myAnd; sOr[wave] = myOr; }
    __syncthreads();
    __shared__ unsigned long long bAnd, bOr;
    if (tid == 0) {
        unsigned long long a = ~0ULL, o = 0ULL;
#pragma unroll
        for (int w = 0; w < 16; ++w) { a &= sAnd[w]; o |= sOr[w]; }
        bAnd = a; bOr = o;
    }

    __shared__ unsigned int hist[NCOPY * HSTRIDE];
    __shared__ unsigned int sWaveTot[4];
    __shared__ unsigned long long sh_prefix;
    __shared__ int sh_r;
    __shared__ int sh_digit, sh_newr, sh_cnt, sh_done;
    if (tid == 0) { sh_prefix = 0ULL; sh_r = topk_p[0]; sh_done = 0; }
    __syncthreads();

    int copy = tid & (NCOPY - 1);
    unsigned int surv = 0xFFFFFFFFu;   // invariant: bit i set <=> key[i] matches sh_prefix

    for (int shift = 56; shift >= 0; shift -= 8) {
        if (sh_done) break;

        unsigned int dA = (unsigned int)(bAnd >> shift) & 255u;
        unsigned int dO = (unsigned int)(bOr  >> shift) & 255u;
        if (dA == dO) {
            // all keys share this digit -> prefix extends, survivors unchanged
            if (tid == 0) sh_prefix |= ((unsigned long long)dA << shift);
            __syncthreads();
            continue;
        }

        // clear histogram copies
        for (int i = tid; i < NCOPY * HSTRIDE; i += T) hist[i] = 0;
        __syncthreads();                                               // B1

        int r = sh_r;

        // histogram only surviving keys (no prefix compare needed)
        unsigned int m = surv;
        while (m) {
            int i = __ffs(m) - 1;
            m &= m - 1;
            unsigned int d = (unsigned int)(key[i] >> shift) & 255u;
            atomicAdd(&hist[copy * HSTRIDE + d], 1u);
        }
        __syncthreads();                                               // B2

        // per-digit totals + wave-level suffix scan over 256 bins (waves 0..3)
        unsigned int vtot = 0, suf = 0, sufn = 0;
        if (tid < 256) {
#pragma unroll
            for (int c = 0; c < NCOPY; ++c) vtot += hist[c * HSTRIDE + tid];
            unsigned int vv = vtot;
            int lane = tid & 63;
#pragma unroll
            for (int off = 1; off < 64; off <<= 1) {
                unsigned int t = __shfl_down(vv, off);
                if (lane + off < 64) vv += t;
            }
            if (lane == 0) sWaveTot[tid >> 6] = vv;
            suf = vv;  // within-wave suffix (bins tid .. end-of-wave)
        }
        __syncthreads();                                               // B3
        if (tid < 256) {
            int lane = tid & 63, w = tid >> 6;
            unsigned int add = 0;
#pragma unroll
            for (int ww = 0; ww < 4; ++ww)
                if (ww > w) add += sWaveTot[ww];
            unsigned int nsuf = __shfl_down(suf, 1);   // next bin's within-wave suffix
            suf += add;
            sufn = ((lane == 63) ? 0u : nsuf) + add;
            if (suf > (unsigned int)r && sufn <= (unsigned int)r) {
                sh_digit = tid;
                sh_newr  = r - (int)sufn;
                sh_cnt   = (int)(suf - sufn);
            }
        }
        __syncthreads();                                               // B4
        if (tid == 0) {
            sh_prefix |= ((unsigned long long)sh_digit << shift);
            sh_r = sh_newr;
        }
        __syncthreads();                                               // B5

        // drop survivors not in the chosen bucket
        unsigned int dsel = (unsigned int)sh_digit;
        m = surv;
        while (m) {
            int i = __ffs(m) - 1;
            m &= m - 1;
            if (((unsigned int)(key[i] >> shift) & 255u) != dsel)
                surv &= ~(1u << i);
        }

        // early exit: unique survivor IS the cutoff key
        if (sh_cnt == 1 && shift > 0) {
            if (surv) {
                int i = __ffs(surv) - 1;
                sh_prefix = key[i];
                sh_done = 1;
            }
        }
        __syncthreads();                                               // B6
    }

    // ---- gather phase: rows with key > cutoff get V copied into out ----
    __shared__ int s_cnt;
    __shared__ int s_idx[MAXSEL];
    if (tid == 0) s_cnt = 0;
    __syncthreads();
    unsigned long long cb = sh_prefix;
#pragma unroll
    for (int i = 0; i < KPT; ++i) {
        if (key[i] > cb) {
            int slot = atomicAdd(&s_cnt, 1);
            if (slot < MAXSEL)
                s_idx[slot] = 2 * (tid + (i >> 1) * T) + (i & 1);
        }
    }
    __syncthreads();
    int cnt = s_cnt < MAXSEL ? s_cnt : MAXSEL;

    int g      = tid >> 4;   // 64 groups of 16 lanes
    int lane16 = tid & 15;
    for (int r = g; r < cnt; r += 64) {
        size_t rowOff = ((size_t)b * LL + s_idx[r]) * DD;
        const f4* vrow = (const f4*)(v + rowOff);
        f4*       orow = (f4*)(out + rowOff);
        orow[lane16] = vrow[lane16];
    }
}

extern "C" void kernel_launch(void* const* d_in, const int* in_sizes, int n_in,
                              void* d_out, int out_size, void* d_ws, size_t ws_size,
                              hipStream_t stream) {
    const float* q = (const float*)d_in[0];
    const float* k = (const float*)d_in[1];
    const float* v = (const float*)d_in[2];
    const int* topk = (const int*)d_in[3];
    float* out = (float*)d_out;

    double* part   = (double*)d_ws;                        // 256 KB, fully written by k1
    double* scores = (double*)((char*)d_ws + 262144);      // 2 MiB, fully written by k2

    k_reduce_q<<<BB * CHUNKS_Q, 256, 0, stream>>>(q, part, out);
    k_scores<<<BB * (LL / 256), 256, 0, stream>>>(k, part, scores, out);
    k_select_gather<<<BB, 1024, 0, stream>>>(scores, topk, v, out);
}

// Round 11
// 75.099 us; speedup vs baseline: 1.1515x; 1.1515x over previous
//
#include <hip/hip_runtime.h>

#define BB 8
#define LL 32768
#define DD 64

typedef float f4 __attribute__((ext_vector_type(4)));
typedef unsigned long long u64x2 __attribute__((ext_vector_type(2)));

// ws layout:
// [0, 256K)            : double part[BB][CHUNKS_Q][DD] partial q-sums (fully written by k1)
// [256K, 256K+BB*LL*8) : double scores[BB*LL]  (2 MiB, fully written by k2)

#define OUT_F4 (BB * LL * DD / 4)  // 4,194,304 float4s in out
#define CHUNKS_Q 64                // blocks per batch in k_reduce_q
#define ROWS_Q (LL / CHUNKS_Q)     // 512 rows per block

// ---------------- Kernel 1: per-chunk partials of sum_l relu(q)+eps ----------------
// 512 blocks x 256 threads (round-8 structure, best measured). Zero-fills first half of out.
__global__ __launch_bounds__(256) void k_reduce_q(const float* __restrict__ q,
                                                  double* __restrict__ part,
                                                  float* __restrict__ out) {
    {
        f4 z = (f4)(0.0f);
        f4* oz = (f4*)out + (size_t)blockIdx.x * 4096 + threadIdx.x;
#pragma unroll
        for (int i = 0; i < 16; ++i) oz[i * 256] = z;
    }

    int b     = blockIdx.x >> 6;           // /CHUNKS_Q
    int chunk = blockIdx.x & (CHUNKS_Q - 1);
    int quad  = threadIdx.x & 15;          // which float4 of the 64-wide row
    int rowg  = threadIdx.x >> 4;          // 16 row-groups

    const f4* qb = (const f4*)(q + (size_t)b * LL * DD);
    const f4* base = qb + (size_t)(chunk * ROWS_Q + rowg) * 16 + quad;

    double a0 = 0.0, a1 = 0.0, a2 = 0.0, a3 = 0.0;
    f4 vb[8];
#pragma unroll
    for (int batch = 0; batch < 4; ++batch) {
#pragma unroll
        for (int j = 0; j < 8; ++j)
            vb[j] = base[(size_t)(batch * 8 + j) * 256];   // 16 rows = 256 f4 stride
#pragma unroll
        for (int j = 0; j < 8; ++j) {
            a0 += (double)fmaxf(vb[j].x, 0.0f) + 1e-3;
            a1 += (double)fmaxf(vb[j].y, 0.0f) + 1e-3;
            a2 += (double)fmaxf(vb[j].z, 0.0f) + 1e-3;
            a3 += (double)fmaxf(vb[j].w, 0.0f) + 1e-3;
        }
    }

    __shared__ double lds[16][16][5];   // [5] pads away bank conflicts
    lds[rowg][quad][0] = a0; lds[rowg][quad][1] = a1;
    lds[rowg][quad][2] = a2; lds[rowg][quad][3] = a3;
    __syncthreads();
    for (int s = 8; s > 0; s >>= 1) {
        if (rowg < s) {
            lds[rowg][quad][0] += lds[rowg + s][quad][0];
            lds[rowg][quad][1] += lds[rowg + s][quad][1];
            lds[rowg][quad][2] += lds[rowg + s][quad][2];
            lds[rowg][quad][3] += lds[rowg + s][quad][3];
        }
        __syncthreads();
    }
    if (rowg == 0) {
        double* pp = part + ((size_t)b * CHUNKS_Q + chunk) * DD;
        pp[quad * 4 + 0] = lds[0][quad][0];
        pp[quad * 4 + 1] = lds[0][quad][1];
        pp[quad * 4 + 2] = lds[0][quad][2];
        pp[quad * 4 + 3] = lds[0][quad][3];
    }
}

// ---------------- Kernel 2: reduce partials -> rq, then scores ----------------
// 1024 blocks x 256 threads (round-8 structure). Zero-fills the SECOND half of out.
__global__ __launch_bounds__(256) void k_scores(const float* __restrict__ k,
                                                const double* __restrict__ part,
                                                double* __restrict__ scores,
                                                float* __restrict__ out) {
    __shared__ double s_part[4][DD];
    __shared__ double s_rq[DD];

    {
        f4 z = (f4)(0.0f);
        f4* oz = (f4*)out + (size_t)(OUT_F4 / 2)
               + (size_t)blockIdx.x * 2048 + threadIdx.x;
#pragma unroll
        for (int i = 0; i < 8; ++i) oz[i * 256] = z;
    }

    const int RPB = 256;
    int b     = blockIdx.x >> 7;          // /(LL/RPB)
    int chunk = blockIdx.x & 127;

    {
        int d = threadIdx.x & 63;
        int g = threadIdx.x >> 6;   // 0..3
        const double* pp = part + (size_t)b * CHUNKS_Q * DD;
        double acc = 0.0;
#pragma unroll
        for (int j = 0; j < 16; ++j)
            acc += pp[(size_t)(g * 16 + j) * DD + d];
        s_part[g][d] = acc;
    }
    __syncthreads();
    if (threadIdx.x < DD) {
        int d = threadIdx.x;
        s_rq[d] = (s_part[0][d] + s_part[1][d]) + (s_part[2][d] + s_part[3][d]);
    }
    __syncthreads();

    int sub   = threadIdx.x & 15;
    int rowIn = threadIdx.x >> 4;

    double r0 = s_rq[sub * 4 + 0];
    double r1 = s_rq[sub * 4 + 1];
    double r2 = s_rq[sub * 4 + 2];
    double r3 = s_rq[sub * 4 + 3];

    const f4* kb = (const f4*)(k + (size_t)b * LL * DD);
    int l0 = chunk * RPB;
    const f4* base = kb + (size_t)(l0 + rowIn) * 16 + sub;

    f4 vb[8];
    double sv[8];
#pragma unroll
    for (int batch = 0; batch < 2; ++batch) {
#pragma unroll
        for (int i = 0; i < 8; ++i)
            vb[i] = base[(size_t)(batch * 8 + i) * 256];
#pragma unroll
        for (int i = 0; i < 8; ++i) {
            sv[i] = r0 * ((double)fmaxf(vb[i].x, 0.0f) + 1e-3)
                  + r1 * ((double)fmaxf(vb[i].y, 0.0f) + 1e-3)
                  + r2 * ((double)fmaxf(vb[i].z, 0.0f) + 1e-3)
                  + r3 * ((double)fmaxf(vb[i].w, 0.0f) + 1e-3);
        }
#pragma unroll
        for (int i = 0; i < 8; ++i) {
            double s = sv[i];
            s += __shfl_xor(s, 1, 16);
            s += __shfl_xor(s, 2, 16);
            s += __shfl_xor(s, 4, 16);
            s += __shfl_xor(s, 8, 16);
            if (sub == 0)
                scores[(size_t)b * LL + l0 + rowIn + 16 * (batch * 8 + i)] = s;
        }
    }
}

// ---------------- Kernel 3: radix select + gather selected V rows ----------------
// One block per batch, 1024 threads, 32 keys/thread — ALL key accesses use
// compile-time indices (predicated unrolled loops) so keys stay in VGPRs (rule #20).
// Survivor bitmask skips dead keys in later passes; wave-level suffix scan
// (~6 barriers/pass vs 21). Early exit on unique bucket.
#define NCOPY 16
#define HSTRIDE 257
#define MAXSEL 96
__global__ __launch_bounds__(1024) void k_select_gather(const double* __restrict__ scores,
                                                        const int* __restrict__ topk_p,
                                                        const float* __restrict__ v,
                                                        float* __restrict__ out) {
    const int T = 1024;
    const int KPT = LL / T;  // 32
    int b   = blockIdx.x;
    int tid = threadIdx.x;

    const u64x2* sb2 = (const u64x2*)(scores + (size_t)b * LL);

    unsigned long long key[KPT];
    unsigned long long myAnd = ~0ULL, myOr = 0ULL;
#pragma unroll
    for (int j = 0; j < KPT / 2; ++j) {
        u64x2 p = sb2[tid + j * T];
        key[2 * j]     = p.x;
        key[2 * j + 1] = p.y;
        myAnd &= p.x & p.y;
        myOr  |= p.x | p.y;
    }

    __shared__ unsigned long long sAnd[16], sOr[16];
#pragma unroll
    for (int off = 32; off >= 1; off >>= 1) {
        myAnd &= __shfl_down(myAnd, off);
        myOr  |= __shfl_down(myOr, off);
    }
    int wave = tid >> 6;
    if ((tid & 63) == 0) { sAnd[wave] = myAnd; sOr[wave] = myOr; }
    __syncthreads();
    __shared__ unsigned long long bAnd, bOr;
    if (tid == 0) {
        unsigned long long a = ~0ULL, o = 0ULL;
#pragma unroll
        for (int w = 0; w < 16; ++w) { a &= sAnd[w]; o |= sOr[w]; }
        bAnd = a; bOr = o;
    }

    __shared__ unsigned int hist[NCOPY * HSTRIDE];
    __shared__ unsigned int sWaveTot[4];
    __shared__ unsigned long long sh_prefix;
    __shared__ int sh_r;
    __shared__ int sh_digit, sh_newr, sh_cnt, sh_done;
    if (tid == 0) { sh_prefix = 0ULL; sh_r = topk_p[0]; sh_done = 0; }
    __syncthreads();

    int copy = tid & (NCOPY - 1);
    unsigned int surv = 0xFFFFFFFFu;   // bit i set <=> key[i] matches sh_prefix so far

    for (int shift = 56; shift >= 0; shift -= 8) {
        if (sh_done) break;

        unsigned int dA = (unsigned int)(bAnd >> shift) & 255u;
        unsigned int dO = (unsigned int)(bOr  >> shift) & 255u;
        if (dA == dO) {
            // digit identical across ALL keys -> prefix extends, survivors unchanged
            if (tid == 0) sh_prefix |= ((unsigned long long)dA << shift);
            __syncthreads();
            continue;
        }

        for (int i = tid; i < NCOPY * HSTRIDE; i += T) hist[i] = 0;
        __syncthreads();                                               // B1

        int r = sh_r;

        // histogram surviving keys only — predicated, compile-time indices
#pragma unroll
        for (int i = 0; i < KPT; ++i) {
            if ((surv >> i) & 1u) {
                unsigned int d = (unsigned int)(key[i] >> shift) & 255u;
                atomicAdd(&hist[copy * HSTRIDE + d], 1u);
            }
        }
        __syncthreads();                                               // B2

        // per-digit totals + wave-level suffix scan over 256 bins (waves 0..3)
        unsigned int suf = 0, sufn = 0;
        if (tid < 256) {
            unsigned int vtot = 0;
#pragma unroll
            for (int c = 0; c < NCOPY; ++c) vtot += hist[c * HSTRIDE + tid];
            unsigned int vv = vtot;
            int lane = tid & 63;
#pragma unroll
            for (int off = 1; off < 64; off <<= 1) {
                unsigned int t = __shfl_down(vv, off);
                if (lane + off < 64) vv += t;
            }
            if (lane == 0) sWaveTot[tid >> 6] = vv;
            suf = vv;  // within-wave suffix (bins tid .. end-of-wave)
        }
        __syncthreads();                                               // B3
        if (tid < 256) {
            int lane = tid & 63, w = tid >> 6;
            unsigned int add = 0;
#pragma unroll
            for (int ww = 0; ww < 4; ++ww)
                if (ww > w) add += sWaveTot[ww];
            unsigned int nsuf = __shfl_down(suf, 1);   // next bin's within-wave suffix
            suf += add;
            sufn = ((lane == 63) ? 0u : nsuf) + add;
            if (suf > (unsigned int)r && sufn <= (unsigned int)r) {
                sh_digit = tid;
                sh_newr  = r - (int)sufn;
                sh_cnt   = (int)(suf - sufn);
            }
        }
        __syncthreads();                                               // B4
        if (tid == 0) {
            sh_prefix |= ((unsigned long long)sh_digit << shift);
            sh_r = sh_newr;
        }
        __syncthreads();                                               // B5

        // drop survivors not in the chosen bucket — predicated, static indices
        unsigned int dsel = (unsigned int)sh_digit;
#pragma unroll
        for (int i = 0; i < KPT; ++i) {
            if (((surv >> i) & 1u) &&
                (((unsigned int)(key[i] >> shift) & 255u) != dsel))
                surv &= ~(1u << i);
        }

        // early exit: unique survivor IS the cutoff key
        if (sh_cnt == 1 && shift > 0 && surv) {
#pragma unroll
            for (int i = 0; i < KPT; ++i) {
                if ((surv >> i) & 1u) {
                    sh_prefix = key[i];
                    sh_done = 1;
                }
            }
        }
        __syncthreads();                                               // B6
    }

    // ---- gather phase: rows with key > cutoff get V copied into out ----
    __shared__ int s_cnt;
    __shared__ int s_idx[MAXSEL];
    if (tid == 0) s_cnt = 0;
    __syncthreads();
    unsigned long long cb = sh_prefix;
#pragma unroll
    for (int i = 0; i < KPT; ++i) {
        if (key[i] > cb) {
            int slot = atomicAdd(&s_cnt, 1);
            if (slot < MAXSEL)
                s_idx[slot] = 2 * (tid + (i >> 1) * T) + (i & 1);
        }
    }
    __syncthreads();
    int cnt = s_cnt < MAXSEL ? s_cnt : MAXSEL;

    int g      = tid >> 4;   // 64 groups of 16 lanes
    int lane16 = tid & 15;
    for (int r = g; r < cnt; r += 64) {
        size_t rowOff = ((size_t)b * LL + s_idx[r]) * DD;
        const f4* vrow = (const f4*)(v + rowOff);
        f4*       orow = (f4*)(out + rowOff);
        orow[lane16] = vrow[lane16];
    }
}

extern "C" void kernel_launch(void* const* d_in, const int* in_sizes, int n_in,
                              void* d_out, int out_size, void* d_ws, size_t ws_size,
                              hipStream_t stream) {
    const float* q = (const float*)d_in[0];
    const float* k = (const float*)d_in[1];
    const float* v = (const float*)d_in[2];
    const int* topk = (const int*)d_in[3];
    float* out = (float*)d_out;

    double* part   = (double*)d_ws;                        // 256 KB, fully written by k1
    double* scores = (double*)((char*)d_ws + 262144);      // 2 MiB, fully written by k2

    k_reduce_q<<<BB * CHUNKS_Q, 256, 0, stream>>>(q, part, out);
    k_scores<<<BB * (LL / 256), 256, 0, stream>>>(k, part, scores, out);
    k_select_gather<<<BB, 1024, 0, stream>>>(scores, topk, v, out);
}

// Round 12
// 61.220 us; speedup vs baseline: 1.4126x; 1.2267x over previous
//
#include <hip/hip_runtime.h>

#define BB 8
#define LL 32768
#define DD 64

typedef float f4 __attribute__((ext_vector_type(4)));
typedef unsigned long long u64x2 __attribute__((ext_vector_type(2)));

// ws layout:
// [0, 256K)            : double part[BB][CHUNKS_Q][DD] partial q-sums (fully written by k1)
// [256K, 256K+BB*LL*8) : double scores[BB*LL]  (2 MiB, fully written by k2)

#define OUT_F4 (BB * LL * DD / 4)  // 4,194,304 float4s in out
#define CHUNKS_Q 64                // blocks per batch in k_reduce_q
#define ROWS_Q (LL / CHUNKS_Q)     // 512 rows per block

// ---------------- Kernel 1: per-chunk partials of sum_l relu(q)+eps ----------------
// 512 blocks x 256 threads (round-8 structure, best measured). Zero-fills first half of out.
__global__ __launch_bounds__(256) void k_reduce_q(const float* __restrict__ q,
                                                  double* __restrict__ part,
                                                  float* __restrict__ out) {
    {
        f4 z = (f4)(0.0f);
        f4* oz = (f4*)out + (size_t)blockIdx.x * 4096 + threadIdx.x;
#pragma unroll
        for (int i = 0; i < 16; ++i) oz[i * 256] = z;
    }

    int b     = blockIdx.x >> 6;           // /CHUNKS_Q
    int chunk = blockIdx.x & (CHUNKS_Q - 1);
    int quad  = threadIdx.x & 15;          // which float4 of the 64-wide row
    int rowg  = threadIdx.x >> 4;          // 16 row-groups

    const f4* qb = (const f4*)(q + (size_t)b * LL * DD);
    const f4* base = qb + (size_t)(chunk * ROWS_Q + rowg) * 16 + quad;

    double a0 = 0.0, a1 = 0.0, a2 = 0.0, a3 = 0.0;
    f4 vb[8];
#pragma unroll
    for (int batch = 0; batch < 4; ++batch) {
#pragma unroll
        for (int j = 0; j < 8; ++j)
            vb[j] = base[(size_t)(batch * 8 + j) * 256];   // 16 rows = 256 f4 stride
#pragma unroll
        for (int j = 0; j < 8; ++j) {
            a0 += (double)fmaxf(vb[j].x, 0.0f) + 1e-3;
            a1 += (double)fmaxf(vb[j].y, 0.0f) + 1e-3;
            a2 += (double)fmaxf(vb[j].z, 0.0f) + 1e-3;
            a3 += (double)fmaxf(vb[j].w, 0.0f) + 1e-3;
        }
    }

    __shared__ double lds[16][16][5];   // [5] pads away bank conflicts
    lds[rowg][quad][0] = a0; lds[rowg][quad][1] = a1;
    lds[rowg][quad][2] = a2; lds[rowg][quad][3] = a3;
    __syncthreads();
    for (int s = 8; s > 0; s >>= 1) {
        if (rowg < s) {
            lds[rowg][quad][0] += lds[rowg + s][quad][0];
            lds[rowg][quad][1] += lds[rowg + s][quad][1];
            lds[rowg][quad][2] += lds[rowg + s][quad][2];
            lds[rowg][quad][3] += lds[rowg + s][quad][3];
        }
        __syncthreads();
    }
    if (rowg == 0) {
        double* pp = part + ((size_t)b * CHUNKS_Q + chunk) * DD;
        pp[quad * 4 + 0] = lds[0][quad][0];
        pp[quad * 4 + 1] = lds[0][quad][1];
        pp[quad * 4 + 2] = lds[0][quad][2];
        pp[quad * 4 + 3] = lds[0][quad][3];
    }
}

// ---------------- Kernel 2: reduce partials -> rq, then scores ----------------
// 1024 blocks x 256 threads (round-8 structure). Zero-fills the SECOND half of out.
__global__ __launch_bounds__(256) void k_scores(const float* __restrict__ k,
                                                const double* __restrict__ part,
                                                double* __restrict__ scores,
                                                float* __restrict__ out) {
    __shared__ double s_part[4][DD];
    __shared__ double s_rq[DD];

    {
        f4 z = (f4)(0.0f);
        f4* oz = (f4*)out + (size_t)(OUT_F4 / 2)
               + (size_t)blockIdx.x * 2048 + threadIdx.x;
#pragma unroll
        for (int i = 0; i < 8; ++i) oz[i * 256] = z;
    }

    const int RPB = 256;
    int b     = blockIdx.x >> 7;          // /(LL/RPB)
    int chunk = blockIdx.x & 127;

    {
        int d = threadIdx.x & 63;
        int g = threadIdx.x >> 6;   // 0..3
        const double* pp = part + (size_t)b * CHUNKS_Q * DD;
        double acc = 0.0;
#pragma unroll
        for (int j = 0; j < 16; ++j)
            acc += pp[(size_t)(g * 16 + j) * DD + d];
        s_part[g][d] = acc;
    }
    __syncthreads();
    if (threadIdx.x < DD) {
        int d = threadIdx.x;
        s_rq[d] = (s_part[0][d] + s_part[1][d]) + (s_part[2][d] + s_part[3][d]);
    }
    __syncthreads();

    int sub   = threadIdx.x & 15;
    int rowIn = threadIdx.x >> 4;

    double r0 = s_rq[sub * 4 + 0];
    double r1 = s_rq[sub * 4 + 1];
    double r2 = s_rq[sub * 4 + 2];
    double r3 = s_rq[sub * 4 + 3];

    const f4* kb = (const f4*)(k + (size_t)b * LL * DD);
    int l0 = chunk * RPB;
    const f4* base = kb + (size_t)(l0 + rowIn) * 16 + sub;

    f4 vb[8];
    double sv[8];
#pragma unroll
    for (int batch = 0; batch < 2; ++batch) {
#pragma unroll
        for (int i = 0; i < 8; ++i)
            vb[i] = base[(size_t)(batch * 8 + i) * 256];
#pragma unroll
        for (int i = 0; i < 8; ++i) {
            sv[i] = r0 * ((double)fmaxf(vb[i].x, 0.0f) + 1e-3)
                  + r1 * ((double)fmaxf(vb[i].y, 0.0f) + 1e-3)
                  + r2 * ((double)fmaxf(vb[i].z, 0.0f) + 1e-3)
                  + r3 * ((double)fmaxf(vb[i].w, 0.0f) + 1e-3);
        }
#pragma unroll
        for (int i = 0; i < 8; ++i) {
            double s = sv[i];
            s += __shfl_xor(s, 1, 16);
            s += __shfl_xor(s, 2, 16);
            s += __shfl_xor(s, 4, 16);
            s += __shfl_xor(s, 8, 16);
            if (sub == 0)
                scores[(size_t)b * LL + l0 + rowIn + 16 * (batch * 8 + i)] = s;
        }
    }
}

// ---------------- Kernel 3: streaming radix select + gather ----------------
// One block per batch, 1024 threads. NO per-thread key array (no spill):
// each pass re-reads the L2-resident 256KB score slice with batched u64x2 loads.
// After a pass leaves few survivors, each thread caches up to 2 matching keys
// in named registers (m0/m1) — later passes + early-exit run from cache.
#define NCOPY 16
#define HSTRIDE 257
#define MAXSEL 96
__global__ __launch_bounds__(1024) void k_select_gather(const double* __restrict__ scores,
                                                        const int* __restrict__ topk_p,
                                                        const float* __restrict__ v,
                                                        float* __restrict__ out) {
    const int T = 1024;
    int b   = blockIdx.x;
    int tid = threadIdx.x;

    const u64x2* sb2 = (const u64x2*)(scores + (size_t)b * LL);

    // ---- Phase 0: AND/OR over all keys (streamed, not retained) ----
    unsigned long long myAnd = ~0ULL, myOr = 0ULL;
#pragma unroll
    for (int batch = 0; batch < 2; ++batch) {
        u64x2 p[8];
#pragma unroll
        for (int j = 0; j < 8; ++j) p[j] = sb2[tid + (batch * 8 + j) * T];
#pragma unroll
        for (int j = 0; j < 8; ++j) { myAnd &= p[j].x & p[j].y; myOr |= p[j].x | p[j].y; }
    }
    __shared__ unsigned long long sAnd[16], sOr[16];
#pragma unroll
    for (int off = 32; off >= 1; off >>= 1) {
        myAnd &= __shfl_down(myAnd, off);
        myOr  |= __shfl_down(myOr, off);
    }
    int wave = tid >> 6;
    if ((tid & 63) == 0) { sAnd[wave] = myAnd; sOr[wave] = myOr; }
    __syncthreads();
    __shared__ unsigned long long bAnd, bOr;
    __shared__ unsigned long long sh_prefix;
    __shared__ int sh_r, sh_digit, sh_newr, sh_cnt, sh_done, sh_ov, sh_cache_ok;
    __shared__ unsigned int hist[NCOPY * HSTRIDE];
    __shared__ unsigned int sWaveTot[4];
    if (tid == 0) {
        unsigned long long a = ~0ULL, o = 0ULL;
#pragma unroll
        for (int w = 0; w < 16; ++w) { a &= sAnd[w]; o |= sOr[w]; }
        bAnd = a; bOr = o;
        sh_prefix = 0ULL; sh_r = topk_p[0]; sh_done = 0; sh_cache_ok = 0;
    }
    __syncthreads();

    int copy = tid & (NCOPY - 1);
    unsigned long long m0 = 0, m1 = 0;   // per-thread cache of prefix-matching keys
    int mcnt = 0;

    for (int shift = 56; shift >= 0; shift -= 8) {
        if (sh_done) break;

        unsigned int dA = (unsigned int)(bAnd >> shift) & 255u;
        unsigned int dO = (unsigned int)(bOr  >> shift) & 255u;
        if (dA == dO) {
            // digit identical across ALL keys: prefix extends, cache stays valid
            if (tid == 0) sh_prefix |= ((unsigned long long)dA << shift);
            __syncthreads();
            continue;
        }

        for (int i = tid; i < NCOPY * HSTRIDE; i += T) hist[i] = 0;
        if (tid == 0) sh_ov = 0;
        __syncthreads();                                               // B1

        int r = sh_r;
        unsigned long long prefix = sh_prefix;
        unsigned long long hm = (shift == 56) ? 0ULL : (~0ULL << (shift + 8));
        int usec = sh_cache_ok;

        if (usec) {
            // cached keys already match prefix
            if (mcnt >= 1) atomicAdd(&hist[copy * HSTRIDE + ((unsigned)(m0 >> shift) & 255u)], 1u);
            if (mcnt >= 2) atomicAdd(&hist[copy * HSTRIDE + ((unsigned)(m1 >> shift) & 255u)], 1u);
        } else {
            mcnt = 0;
#pragma unroll
            for (int batch = 0; batch < 2; ++batch) {
                u64x2 p[8];
#pragma unroll
                for (int j = 0; j < 8; ++j) p[j] = sb2[tid + (batch * 8 + j) * T];
#pragma unroll
                for (int j = 0; j < 8; ++j) {
                    unsigned long long ka = p[j].x, kb2 = p[j].y;
                    if ((ka & hm) == prefix) {
                        atomicAdd(&hist[copy * HSTRIDE + ((unsigned)(ka >> shift) & 255u)], 1u);
                        if (mcnt == 0) m0 = ka; else if (mcnt == 1) m1 = ka;
                        ++mcnt;
                    }
                    if ((kb2 & hm) == prefix) {
                        atomicAdd(&hist[copy * HSTRIDE + ((unsigned)(kb2 >> shift) & 255u)], 1u);
                        if (mcnt == 0) m0 = kb2; else if (mcnt == 1) m1 = kb2;
                        ++mcnt;
                    }
                }
            }
            if (mcnt > 2) sh_ov = 1;   // plain store: any writer sets 1
        }
        __syncthreads();                                               // B2

        // per-digit totals + wave-level suffix scan over 256 bins
        unsigned int suf = 0, sufn = 0;
        if (tid < 256) {
            unsigned int vtot = 0;
#pragma unroll
            for (int c = 0; c < NCOPY; ++c) vtot += hist[c * HSTRIDE + tid];
            unsigned int vv = vtot;
            int lane = tid & 63;
#pragma unroll
            for (int off = 1; off < 64; off <<= 1) {
                unsigned int t = __shfl_down(vv, off);
                if (lane + off < 64) vv += t;
            }
            if (lane == 0) sWaveTot[tid >> 6] = vv;
            suf = vv;
        }
        __syncthreads();                                               // B3
        if (tid < 256) {
            int lane = tid & 63, w = tid >> 6;
            unsigned int add = 0;
#pragma unroll
            for (int ww = 0; ww < 4; ++ww)
                if (ww > w) add += sWaveTot[ww];
            unsigned int nsuf = __shfl_down(suf, 1);
            suf += add;
            sufn = ((lane == 63) ? 0u : nsuf) + add;
            if (suf > (unsigned int)r && sufn <= (unsigned int)r) {
                sh_digit = tid;
                sh_newr  = r - (int)sufn;
                sh_cnt   = (int)(suf - sufn);
            }
        }
        __syncthreads();                                               // B4
        if (tid == 0) {
            sh_prefix |= ((unsigned long long)sh_digit << shift);
            sh_r = sh_newr;
            if (!usec) sh_cache_ok = (sh_ov == 0);
        }
        __syncthreads();                                               // B5

        // filter cache by chosen digit (static, named registers only)
        {
            unsigned int dsel = (unsigned int)sh_digit;
            unsigned long long n0 = 0, n1 = 0;
            int nm = 0;
            if (mcnt >= 1 && (((unsigned)(m0 >> shift) & 255u) == dsel)) { n0 = m0; nm = 1; }
            if (mcnt >= 2 && (((unsigned)(m1 >> shift) & 255u) == dsel)) {
                if (nm == 0) n0 = m1; else n1 = m1;
                ++nm;
            }
            m0 = n0; m1 = n1; mcnt = nm;
        }

        // early exit: unique survivor IS the cutoff key (needs valid cache)
        if (sh_cnt == 1 && sh_cache_ok && shift > 0) {
            if (mcnt >= 1) {           // exactly one thread block-wide
                sh_prefix = m0;
                sh_done = 1;
            }
        }
        __syncthreads();                                               // B6
    }

    // ---- gather: stream keys once more, copy V rows with key > cutoff ----
    __shared__ int s_cnt;
    __shared__ int s_idx[MAXSEL];
    if (tid == 0) s_cnt = 0;
    __syncthreads();
    unsigned long long cb = sh_prefix;
#pragma unroll
    for (int batch = 0; batch < 2; ++batch) {
        u64x2 p[8];
#pragma unroll
        for (int j = 0; j < 8; ++j) p[j] = sb2[tid + (batch * 8 + j) * T];
#pragma unroll
        for (int j = 0; j < 8; ++j) {
            int jj = batch * 8 + j;
            if (p[j].x > cb) {
                int slot = atomicAdd(&s_cnt, 1);
                if (slot < MAXSEL) s_idx[slot] = 2 * (tid + jj * T);
            }
            if (p[j].y > cb) {
                int slot = atomicAdd(&s_cnt, 1);
                if (slot < MAXSEL) s_idx[slot] = 2 * (tid + jj * T) + 1;
            }
        }
    }
    __syncthreads();
    int cnt = s_cnt < MAXSEL ? s_cnt : MAXSEL;

    int g      = tid >> 4;   // 64 groups of 16 lanes
    int lane16 = tid & 15;
    for (int r = g; r < cnt; r += 64) {
        size_t rowOff = ((size_t)b * LL + s_idx[r]) * DD;
        const f4* vrow = (const f4*)(v + rowOff);
        f4*       orow = (f4*)(out + rowOff);
        orow[lane16] = vrow[lane16];
    }
}

extern "C" void kernel_launch(void* const* d_in, const int* in_sizes, int n_in,
                              void* d_out, int out_size, void* d_ws, size_t ws_size,
                              hipStream_t stream) {
    const float* q = (const float*)d_in[0];
    const float* k = (const float*)d_in[1];
    const float* v = (const float*)d_in[2];
    const int* topk = (const int*)d_in[3];
    float* out = (float*)d_out;

    double* part   = (double*)d_ws;                        // 256 KB, fully written by k1
    double* scores = (double*)((char*)d_ws + 262144);      // 2 MiB, fully written by k2

    k_reduce_q<<<BB * CHUNKS_Q, 256, 0, stream>>>(q, part, out);
    k_scores<<<BB * (LL / 256), 256, 0, stream>>>(k, part, scores, out);
    k_select_gather<<<BB, 1024, 0, stream>>>(scores, topk, v, out);
}